// Round 6
// baseline (325.801 us; speedup 1.0000x reference)
//
#include <hip/hip_runtime.h>

typedef __attribute__((ext_vector_type(8))) short s8v;   // 8 x bf16 (4 VGPRs)
typedef __attribute__((ext_vector_type(4))) float f4v;   // MFMA accumulator
typedef _Float16 h4 __attribute__((ext_vector_type(4))); // 4 x f16 (2 VGPRs)
typedef unsigned short u16;
typedef unsigned long long u64;

#define DM 512
#define NH 8
#define HD 64
#define BB 4
#define NN 2048

__device__ __forceinline__ float bf2f(u16 x){ return __uint_as_float(((unsigned)x)<<16); }
__device__ __forceinline__ u16 f2bf(float f){
  unsigned u = __float_as_uint(f);
  u += 0x7FFFu + ((u>>16)&1u);            // round-to-nearest-even
  return (u16)(u>>16);
}
// async global->LDS, 16B per lane; LDS dest = wave-uniform base + lane*16
__device__ __forceinline__ void gl2lds16(const u16* g, u16* l){
  __builtin_amdgcn_global_load_lds((__attribute__((address_space(1))) void*)(g),
                                   (__attribute__((address_space(3))) void*)(l), 16, 0, 0);
}

// ---------------------------------------------------------------------------
// Kernel 1: permute + bf16-convert weights/biases (f32 inputs).
// ---------------------------------------------------------------------------
__global__ void k_permute(const float* Wq, const float* bq, const float* Wk, const float* bk,
                          const float* Wv, const float* bv, const float* Wm,
                          u16* Wp, u16* Wmp, float* bp){
  int blk = blockIdx.x, tid = threadIdx.x;
  if (blk < 1536){
    int t = blk >> 9, op = blk & 511;
    int srow = ((op & 63) << 3) | (op >> 6);
    const float* W = (t==0) ? Wq : ((t==1) ? Wk : Wv);
    for (int j = tid; j < 512; j += 256)
      Wp[((size_t)t*512 + op)*512 + j] = f2bf(W[(size_t)srow*512 + j]);
  } else if (blk < 2048){
    int o = blk - 1536;
    for (int c = tid; c < 512; c += 256){
      int scol = ((c & 63) << 3) | (c >> 6);
      Wmp[(size_t)o*512 + c] = f2bf(Wm[(size_t)o*512 + scol]);
    }
  } else {
    for (int idx = tid; idx < 1536; idx += 256){
      int t = idx >> 9, op = idx & 511;
      const float* bs = (t==0) ? bq : ((t==1) ? bk : bv);
      int srow = ((op & 63) << 3) | (op >> 6);
      bp[idx] = bs[srow];
    }
  }
}

// ---------------------------------------------------------------------------
// Kernel 2: transpose + convert inputs  f32 [b][i][r] -> bf16 XT[t][b][r][i]
// ---------------------------------------------------------------------------
__global__ __launch_bounds__(256) void k_transpose(const float* q, const float* k, const float* v, u16* XT){
  __shared__ u16 T[64*72];
  int blk = blockIdx.x, tid = threadIdx.x;
  int rt = blk & 31; blk >>= 5;
  int it = blk & 7;  blk >>= 3;
  int b  = blk & 3;  int t = blk >> 2;
  const float* src = (t==0) ? q : ((t==1) ? k : v);
  src += (size_t)b*DM*NN;
  int i0 = it*64, r0 = rt*64;
  int il = tid>>4, rj = (tid&15)*4;
  #pragma unroll
  for (int p=0;p<4;p++){
    int i = il + p*16;
    float4 vv = *(const float4*)&src[(size_t)(i0+i)*NN + r0 + rj];
    float fv[4] = {vv.x, vv.y, vv.z, vv.w};
    #pragma unroll
    for (int qq=0;qq<4;qq++){
      int r = rj + qq;
      int sr = ((r&3)<<4) | (r>>2);
      T[sr*72 + i] = f2bf(fv[qq]);
    }
  }
  __syncthreads();
  u16* dst = XT + ((size_t)(t*4+b)*NN)*DM;
  int rl = tid>>3, ib = (tid&7)*8;
  #pragma unroll
  for (int p=0;p<2;p++){
    int r = rl + p*32;
    int sr = ((r&3)<<4) | (r>>2);
    s8v vv = *(s8v*)&T[sr*72 + ib];
    *(s8v*)&dst[(size_t)(r0+r)*DM + i0 + ib] = vv;
  }
}

// ---------------------------------------------------------------------------
// Kernel 3: projection GEMM, m97-style 128x128 tile, BK=32, global_load_lds.
// t=0 (Q, scaled 1/8) / t=1 (K) -> P[t*4+b][h][r][d] bf16 (LDS-staged, coalesced)
// t=2 (V) -> VT[b][h][d][m]  f16 (PV MFMA runs in f16)
// ---------------------------------------------------------------------------
__global__ __launch_bounds__(256) void k_proj(const u16* XT, const u16* Wp, const float* bp,
                                              u16* P, u16* VT){
  __shared__ u16 Al[128*32];
  __shared__ u16 Bl[128*32];
  __shared__ u16 S[128*72];
  int blk = blockIdx.x, tid = threadIdx.x;
  int nt = blk & 3; int mt = blk >> 2;      // 192 M-tiles
  int tb = mt >> 4;                         // t*4+b
  int t  = tb >> 2, b = tb & 3;
  int r0 = (mt & 15)*128, o0 = nt*128;
  const u16* Abase = XT + ((size_t)tb*NN + r0)*DM;
  const u16* Bbase = Wp + ((size_t)t*512 + o0)*DM;

  int w = tid>>6, L = tid&63, li = L&15, lq = L>>4;
  int wr = w>>1, wc = w&1;
  int srow = tid>>2;
  int g8   = ((tid&3) ^ ((tid>>3)&3))*8;
  u16* AldsW = &Al[((tid&192))*8];
  u16* BldsW = &Bl[((tid&192))*8];
  int sw = (li>>1)&3;

  f4v acc[4][4];
  #pragma unroll
  for (int a=0;a<4;a++)
    #pragma unroll
    for (int c2=0;c2<4;c2++) acc[a][c2] = (f4v){0.f,0.f,0.f,0.f};

  for (int kk=0; kk<16; kk++){
    int k0 = kk*32;
    __syncthreads();
    #pragma unroll
    for (int c=0;c<2;c++){
      gl2lds16(&Abase[(size_t)(srow + c*64)*DM + k0 + g8], AldsW + c*2048);
      gl2lds16(&Bbase[(size_t)(srow + c*64)*DM + k0 + g8], BldsW + c*2048);
    }
    __syncthreads();
    s8v af[4], bfr[4];
    #pragma unroll
    for (int a=0;a<4;a++){
      int r = wr*64 + a*16 + li;
      af[a] = *(s8v*)&Al[r*32 + ((lq ^ sw))*8];
    }
    #pragma unroll
    for (int c2=0;c2<4;c2++){
      int r = wc*64 + c2*16 + li;
      bfr[c2] = *(s8v*)&Bl[r*32 + ((lq ^ sw))*8];
    }
    #pragma unroll
    for (int a=0;a<4;a++)
      #pragma unroll
      for (int c2=0;c2<4;c2++)
        acc[a][c2] = __builtin_amdgcn_mfma_f32_16x16x32_bf16(af[a], bfr[c2], acc[a][c2], 0, 0, 0);
  }

  if (t < 2){
    float scale = (t==0) ? 0.125f : 1.0f;
    // 2 passes of 64 cols (one head each): LDS-stage, then coalesced b128 stores
    #pragma unroll
    for (int p=0;p<2;p++){
      if (wc == p){
        #pragma unroll
        for (int c2=0;c2<4;c2++){
          int cl = c2*16 + li;
          float bias = bp[t*512 + o0 + p*64 + cl];
          #pragma unroll
          for (int a=0;a<4;a++)
            #pragma unroll
            for (int ri=0;ri<4;ri++)
              S[(wr*64 + a*16 + lq*4 + ri)*72 + cl] = f2bf((acc[a][c2][ri] + bias)*scale);
        }
      }
      __syncthreads();
      int row = tid>>1, cb = (tid&1)*32;
      int hh = (o0>>6) + p;
      u16* Pb = P + (((size_t)tb*NH + hh)*NN + r0 + row)*HD + cb;
      #pragma unroll
      for (int c=0;c<4;c++){
        s8v vv = *(s8v*)&S[row*72 + cb + c*8];
        *(s8v*)&Pb[c*8] = vv;
      }
      __syncthreads();
    }
  } else {
    // V: transpose epilogue (f16 bits), 2 passes of 64 cols (one head each)
    #pragma unroll
    for (int p=0;p<2;p++){
      if (wc == p){
        #pragma unroll
        for (int c2=0;c2<4;c2++){
          int cl = c2*16 + li;
          float bias = bp[2*512 + o0 + p*64 + cl];
          #pragma unroll
          for (int a=0;a<4;a++)
            #pragma unroll
            for (int ri=0;ri<4;ri++){
              _Float16 hh = (_Float16)(acc[a][c2][ri] + bias);
              S[(wr*64 + a*16 + lq*4 + ri)*72 + cl] = *(const u16*)&hh;
            }
        }
      }
      __syncthreads();
      int dl = tid & 63;
      u16* Vb = VT + (((size_t)b*NH + (o0>>6) + p)*HD + dl)*NN + r0;
      #pragma unroll
      for (int it2=0; it2<4; it2++){
        int mseg = (tid>>6) + it2*4;
        s8v vv; u16* vp = (u16*)&vv;
        #pragma unroll
        for (int j=0;j<8;j++) vp[j] = S[(mseg*8+j)*72 + dl];
        *(s8v*)&Vb[mseg*8] = vv;
      }
      __syncthreads();
    }
  }
}

// ---------------------------------------------------------------------------
// Kernel 4: bit-pack mask. allowed iff M==1.
// ---------------------------------------------------------------------------
__global__ void k_maskpack(const int* M, u64* bits){
  int tid = threadIdx.x;
  size_t word = (size_t)blockIdx.x*4 + (tid>>6);
  int lane = tid & 63;
  int v = M[word*64 + lane];
  u64 bal = __ballot(v == 1);
  if (lane == 0) bits[word] = bal;
}

// ---------------------------------------------------------------------------
// Kernel 4b: per-(b,ntile,mtile) AND of mask words -> fast-path flags.
// ---------------------------------------------------------------------------
__global__ __launch_bounds__(256) void k_maskand(const u64* bits, u64* allw){
  __shared__ u64 red[256];
  int bnt = blockIdx.x, tid = threadIdx.x;
  int mt = tid & 31, rg = tid >> 5;
  const u64* base = bits + (size_t)bnt*64*32;
  u64 v = ~0ull;
  #pragma unroll
  for (int j=0;j<8;j++) v &= base[(size_t)(rg*8+j)*32 + mt];
  red[tid] = v;
  __syncthreads();
  if (tid < 32){
    u64 a = red[tid];
    #pragma unroll
    for (int g2=1; g2<8; g2++) a &= red[g2*32 + tid];
    allw[(size_t)bnt*32 + tid] = a;
  }
}

// ---------------------------------------------------------------------------
// Kernel 5: transposed-S flash, BARRIER-FREE main loop.
// Each wave owns m-slice [w*16,w*16+16) and loads its K/V fragments DIRECTLY
// from global (L2/L3-resident; K-frag = 16 fully-covered 64B lines per instr).
// S^T C-regs feed PV's B-fragment in-register (16x16x16 f16). LDS used only
// for the one-time cross-wave O^T reduction at the end.
// ---------------------------------------------------------------------------
__global__ __launch_bounds__(256) void k_flash(const u16* Pq, const u16* VT, const u64* bits,
                                               const u64* allw, u16* Xout){
  __shared__ __align__(16) char smem[18432 + 1024];
  float* Red = (float*)smem;               // [64][68] f32
  float* lsb = (float*)(smem + 18432);     // [4][64]

  int blk = blockIdx.x, tid = threadIdx.x;
  int nt = blk & 31; int bh = blk >> 5;
  int b = bh >> 3;
  int n0 = nt*64;
  const size_t TSZ = (size_t)BB*NH*NN*HD;
  const u16* Qb = Pq + ((size_t)bh*NN + n0)*HD;
  const u16* Kb = Pq + TSZ + (size_t)bh*NN*HD;
  const u16* Vb = VT + (size_t)bh*HD*NN;          // [d][m] f16
  const u64* awp = allw + ((size_t)b*32 + nt)*32;

  int w = tid>>6, L = tid&63, li = L&15, lq = L>>4;

  // Q fragments in registers (loop-invariant)
  s8v Qf[4][2];
  #pragma unroll
  for (int j=0;j<4;j++)
    #pragma unroll
    for (int h2=0;h2<2;h2++)
      Qf[j][h2] = *(const s8v*)&Qb[(size_t)(j*16+li)*HD + h2*32 + lq*8];

  f4v O[4][4];     // O^T partial: [d-block j2][n-block j]
  #pragma unroll
  for (int j2=0;j2<4;j2++)
    #pragma unroll
    for (int j=0;j<4;j++) O[j2][j] = (f4v){0.f,0.f,0.f,0.f};
  float ls[4] = {0.f,0.f,0.f,0.f};

  const u16* Krow = Kb + (size_t)(w*16 + li)*HD + lq*8;     // + m0*HD
  const u16* Vrow = Vb + (size_t)li*NN + w*16 + lq*4;       // + j2*16*NN + m0

  for (int mt=0; mt<32; mt++){
    int m0 = mt*64;
    u64 aw = awp[mt];
    bool fast = (aw == ~0ull);

    // direct global fragment loads (no LDS, no barriers)
    s8v Kf0 = *(const s8v*)&Krow[(size_t)m0*HD];
    s8v Kf1 = *(const s8v*)&Krow[(size_t)m0*HD + 32];
    h4 Vf[4];
    #pragma unroll
    for (int j2=0;j2<4;j2++)
      Vf[j2] = *(const h4*)&Vrow[(size_t)(j2*16)*NN + m0];

    // S^T[m=w-slice][n] = K Q^T : lane holds P[n=j*16+li][m=lq*4+r]
    f4v S[4];
    #pragma unroll
    for (int j=0;j<4;j++){
      f4v c = (f4v){0.f,0.f,0.f,0.f};
      c = __builtin_amdgcn_mfma_f32_16x16x32_bf16(Kf0, Qf[j][0], c, 0, 0, 0);
      c = __builtin_amdgcn_mfma_f32_16x16x32_bf16(Kf1, Qf[j][1], c, 0, 0, 0);
      S[j] = c;
    }

    // exp (+mask), accumulate partials, pack to f16 B-fragments
    h4 Pf[4];
    if (fast){
      #pragma unroll
      for (int j=0;j<4;j++){
        float e0 = __expf(S[j][0]), e1 = __expf(S[j][1]);
        float e2 = __expf(S[j][2]), e3 = __expf(S[j][3]);
        ls[j] += (e0+e1)+(e2+e3);
        Pf[j][0] = (_Float16)e0; Pf[j][1] = (_Float16)e1;
        Pf[j][2] = (_Float16)e2; Pf[j][3] = (_Float16)e3;
      }
    } else {
      int mbit = w*16 + lq*4;
      #pragma unroll
      for (int j=0;j<4;j++){
        u64 mw = bits[((size_t)b*NN + n0 + j*16 + li)*32 + mt];
        float e[4];
        #pragma unroll
        for (int r=0;r<4;r++){
          float ev = __expf(S[j][r]);
          e[r] = ((mw>>(mbit+r)) & 1ull) ? ev : 0.f;
          Pf[j][r] = (_Float16)e[r];
        }
        ls[j] += (e[0]+e[1])+(e[2]+e[3]);
      }
    }

    // O^T += V^T P (all operands in registers)
    #pragma unroll
    for (int j2=0;j2<4;j2++)
      #pragma unroll
      for (int j=0;j<4;j++)
        O[j2][j] = __builtin_amdgcn_mfma_f32_16x16x16f16(Vf[j2], Pf[j], O[j2][j], 0, 0, 0);
  }

  // reduce ls over lq (lanes li, li+16, li+32, li+48)
  #pragma unroll
  for (int j=0;j<4;j++){
    float r = ls[j];
    r += __shfl_xor(r, 16); r += __shfl_xor(r, 32);
    ls[j] = r;
  }
  if (lq == 0){
    #pragma unroll
    for (int j=0;j<4;j++) lsb[w*64 + j*16 + li] = ls[j];
  }
  __syncthreads();

  // cross-wave O^T reduction into Red[n][d] (4 phases)
  #pragma unroll
  for (int ph=0; ph<4; ph++){
    if (w == ph){
      #pragma unroll
      for (int j=0;j<4;j++)
        #pragma unroll
        for (int j2=0;j2<4;j2++){
          f4v* p = (f4v*)&Red[(j*16+li)*68 + j2*16 + lq*4];
          if (ph == 0) *p = O[j2][j];
          else { f4v t = *p; t += O[j2][j]; *p = t; }
        }
    }
    __syncthreads();
  }

  // normalize + write Xout[b][n][h*64+d]
  int n = tid>>2, d0 = (tid&3)*16;
  float s = lsb[n] + lsb[64+n] + lsb[128+n] + lsb[192+n];
  float inv = (s > 0.f) ? 1.0f/s : 0.f;
  int h = bh & 7;
  u16* Xo = Xout + ((size_t)b*NN + n0 + n)*DM + h*HD + d0;
  u16 tmp[16];
  #pragma unroll
  for (int e2=0;e2<4;e2++){
    f4v vv = *(f4v*)&Red[n*68 + d0 + e2*4];
    #pragma unroll
    for (int q2=0;q2<4;q2++) tmp[e2*4+q2] = f2bf(vv[q2]*inv);
  }
  *(s8v*)&Xo[0] = *(s8v*)&tmp[0];
  *(s8v*)&Xo[8] = *(s8v*)&tmp[8];
}

// ---------------------------------------------------------------------------
// Kernel 6: output GEMM, 64(o) x 128(n) tiles -> 512 blocks (2/CU).
// A=Wmp (o rows), B=Xout (n rows). out[b][o][n] = acc + bm[o] (f32)
// ---------------------------------------------------------------------------
__global__ __launch_bounds__(256) void k_out(const u16* Wmp, const u16* Xout, const float* bm, float* out){
  __shared__ u16 Al[64*32];
  __shared__ u16 Bl[128*32];
  int blk = blockIdx.x, tid = threadIdx.x;
  int nt = blk & 15; blk >>= 4;
  int ot = blk & 7;  int b = blk >> 3;
  int o0 = ot*64, n0 = nt*128;
  const u16* Abase = Wmp + (size_t)o0*DM;
  const u16* Bbase = Xout + ((size_t)b*NN + n0)*DM;

  int w = tid>>6, L = tid&63, li = L&15, lq = L>>4;
  int wo = w&1, wn = w>>1;
  int srow = tid>>2;
  int g8   = ((tid&3) ^ ((tid>>3)&3))*8;
  u16* AldsW = &Al[((tid&192))*8];
  u16* BldsW = &Bl[((tid&192))*8];
  int sw = (li>>1)&3;

  f4v acc[2][4];
  #pragma unroll
  for (int a=0;a<2;a++)
    #pragma unroll
    for (int c2=0;c2<4;c2++) acc[a][c2] = (f4v){0.f,0.f,0.f,0.f};

  for (int kk=0; kk<16; kk++){
    int k0 = kk*32;
    __syncthreads();
    gl2lds16(&Abase[(size_t)srow*DM + k0 + g8], AldsW);
    #pragma unroll
    for (int c=0;c<2;c++)
      gl2lds16(&Bbase[(size_t)(srow + c*64)*DM + k0 + g8], BldsW + c*2048);
    __syncthreads();
    s8v af[2], bfr[4];
    #pragma unroll
    for (int a=0;a<2;a++){
      int r = wo*32 + a*16 + li;
      af[a] = *(s8v*)&Al[r*32 + ((lq ^ sw))*8];
    }
    #pragma unroll
    for (int c2=0;c2<4;c2++){
      int r = wn*64 + c2*16 + li;
      bfr[c2] = *(s8v*)&Bl[r*32 + ((lq ^ sw))*8];
    }
    #pragma unroll
    for (int a=0;a<2;a++)
      #pragma unroll
      for (int c2=0;c2<4;c2++)
        acc[a][c2] = __builtin_amdgcn_mfma_f32_16x16x32_bf16(af[a], bfr[c2], acc[a][c2], 0, 0, 0);
  }

  #pragma unroll
  for (int a=0;a<2;a++){
    #pragma unroll
    for (int ri=0;ri<4;ri++){
      int o = o0 + wo*32 + a*16 + lq*4 + ri;
      float bias = bm[o];
      float* ob = out + ((size_t)b*DM + o)*NN + n0 + wn*64;
      #pragma unroll
      for (int c2=0;c2<4;c2++)
        ob[c2*16 + li] = acc[a][c2][ri] + bias;
    }
  }
}

// ---------------------------------------------------------------------------
extern "C" void kernel_launch(void* const* d_in, const int* in_sizes, int n_in,
                              void* d_out, int out_size, void* d_ws, size_t ws_size,
                              hipStream_t stream){
  const float* q  = (const float*)d_in[0];
  const float* k  = (const float*)d_in[1];
  const float* v  = (const float*)d_in[2];
  const int*   M  = (const int*)d_in[3];
  const float* Wq = (const float*)d_in[4];
  const float* bq = (const float*)d_in[5];
  const float* Wk = (const float*)d_in[6];
  const float* bk = (const float*)d_in[7];
  const float* Wv = (const float*)d_in[8];
  const float* bv = (const float*)d_in[9];
  const float* Wm = (const float*)d_in[10];
  const float* bm = (const float*)d_in[11];

  char* ws = (char*)d_ws;
  u16*   XT   = (u16*)(ws + 0);            // 25,165,824
  u16*   P    = (u16*)(ws + 25165824);     // Q,K: 16,777,216
  u16*   VT   = (u16*)(ws + 41943040);     //  8,388,608 (f16)
  u16*   Wp   = (u16*)(ws + 50331648);     //  1,572,864
  u16*   Wmp  = (u16*)(ws + 51904512);     //    524,288
  float* bp   = (float*)(ws + 52428800);   //      6,144
  u64*   bits = (u64*)(ws + 52434944);     //  2,097,152
  u16*   Xout = (u16*)(ws + 54532096);     //  8,388,608
  u64*   allw = (u64*)(ws + 62920704);     //     32,768
  float* out  = (float*)d_out;

  k_permute<<<2049, 256, 0, stream>>>(Wq, bq, Wk, bk, Wv, bv, Wm, Wp, Wmp, bp);
  k_transpose<<<3072, 256, 0, stream>>>(q, k, v, XT);
  k_proj<<<768, 256, 0, stream>>>(XT, Wp, bp, P, VT);
  k_maskpack<<<65536, 256, 0, stream>>>(M, bits);
  k_maskand<<<128, 256, 0, stream>>>(bits, allw);
  k_flash<<<1024, 256, 0, stream>>>(P, VT, bits, allw, Xout);
  k_out<<<512, 256, 0, stream>>>(Wmp, Xout, bm, out);
}

// Round 7
// 286.220 us; speedup vs baseline: 1.1383x; 1.1383x over previous
//
#include <hip/hip_runtime.h>

typedef __attribute__((ext_vector_type(8))) short s8v;   // 8 x bf16 (4 VGPRs)
typedef __attribute__((ext_vector_type(4))) float f4v;   // MFMA accumulator
typedef _Float16 h4 __attribute__((ext_vector_type(4))); // 4 x f16 (2 VGPRs)
typedef unsigned short u16;
typedef unsigned long long u64;

#define DM 512
#define NH 8
#define HD 64
#define BB 4
#define NN 2048

__device__ __forceinline__ float bf2f(u16 x){ return __uint_as_float(((unsigned)x)<<16); }
__device__ __forceinline__ u16 f2bf(float f){
  unsigned u = __float_as_uint(f);
  u += 0x7FFFu + ((u>>16)&1u);            // round-to-nearest-even
  return (u16)(u>>16);
}
// async global->LDS, 16B per lane; LDS dest = wave-uniform base + lane*16
__device__ __forceinline__ void gl2lds16(const u16* g, u16* l){
  __builtin_amdgcn_global_load_lds((__attribute__((address_space(1))) void*)(g),
                                   (__attribute__((address_space(3))) void*)(l), 16, 0, 0);
}

// ---------------------------------------------------------------------------
// Kernel 1: permute + bf16-convert weights/biases (f32 inputs).
// ---------------------------------------------------------------------------
__global__ void k_permute(const float* Wq, const float* bq, const float* Wk, const float* bk,
                          const float* Wv, const float* bv, const float* Wm,
                          u16* Wp, u16* Wmp, float* bp){
  int blk = blockIdx.x, tid = threadIdx.x;
  if (blk < 1536){
    int t = blk >> 9, op = blk & 511;
    int srow = ((op & 63) << 3) | (op >> 6);
    const float* W = (t==0) ? Wq : ((t==1) ? Wk : Wv);
    for (int j = tid; j < 512; j += 256)
      Wp[((size_t)t*512 + op)*512 + j] = f2bf(W[(size_t)srow*512 + j]);
  } else if (blk < 2048){
    int o = blk - 1536;
    for (int c = tid; c < 512; c += 256){
      int scol = ((c & 63) << 3) | (c >> 6);
      Wmp[(size_t)o*512 + c] = f2bf(Wm[(size_t)o*512 + scol]);
    }
  } else {
    for (int idx = tid; idx < 1536; idx += 256){
      int t = idx >> 9, op = idx & 511;
      const float* bs = (t==0) ? bq : ((t==1) ? bk : bv);
      int srow = ((op & 63) << 3) | (op >> 6);
      bp[idx] = bs[srow];
    }
  }
}

// ---------------------------------------------------------------------------
// Kernel 2: transpose + convert inputs  f32 [b][i][r] -> bf16 XT[t][b][r][i]
// ---------------------------------------------------------------------------
__global__ __launch_bounds__(256) void k_transpose(const float* q, const float* k, const float* v, u16* XT){
  __shared__ u16 T[64*72];
  int blk = blockIdx.x, tid = threadIdx.x;
  int rt = blk & 31; blk >>= 5;
  int it = blk & 7;  blk >>= 3;
  int b  = blk & 3;  int t = blk >> 2;
  const float* src = (t==0) ? q : ((t==1) ? k : v);
  src += (size_t)b*DM*NN;
  int i0 = it*64, r0 = rt*64;
  int il = tid>>4, rj = (tid&15)*4;
  #pragma unroll
  for (int p=0;p<4;p++){
    int i = il + p*16;
    float4 vv = *(const float4*)&src[(size_t)(i0+i)*NN + r0 + rj];
    float fv[4] = {vv.x, vv.y, vv.z, vv.w};
    #pragma unroll
    for (int qq=0;qq<4;qq++){
      int r = rj + qq;
      int sr = ((r&3)<<4) | (r>>2);
      T[sr*72 + i] = f2bf(fv[qq]);
    }
  }
  __syncthreads();
  u16* dst = XT + ((size_t)(t*4+b)*NN)*DM;
  int rl = tid>>3, ib = (tid&7)*8;
  #pragma unroll
  for (int p=0;p<2;p++){
    int r = rl + p*32;
    int sr = ((r&3)<<4) | (r>>2);
    s8v vv = *(s8v*)&T[sr*72 + ib];
    *(s8v*)&dst[(size_t)(r0+r)*DM + i0 + ib] = vv;
  }
}

// ---------------------------------------------------------------------------
// Kernel 3: projection GEMM, m97-style 128x128 tile, BK=32, global_load_lds.
// t=0 (Q, scaled 1/8) / t=1 (K) -> P[t*4+b][h][r][d] bf16 (LDS-staged, coalesced)
// t=2 (V) -> VT2[b][h][m/16][d][m%16]  f16, fragment-native tiled layout
// ---------------------------------------------------------------------------
__global__ __launch_bounds__(256) void k_proj(const u16* XT, const u16* Wp, const float* bp,
                                              u16* P, u16* VT){
  __shared__ u16 Al[128*32];
  __shared__ u16 Bl[128*32];
  __shared__ u16 S[128*72];
  int blk = blockIdx.x, tid = threadIdx.x;
  int nt = blk & 3; int mt = blk >> 2;      // 192 M-tiles
  int tb = mt >> 4;                         // t*4+b
  int t  = tb >> 2, b = tb & 3;
  int r0 = (mt & 15)*128, o0 = nt*128;
  const u16* Abase = XT + ((size_t)tb*NN + r0)*DM;
  const u16* Bbase = Wp + ((size_t)t*512 + o0)*DM;

  int w = tid>>6, L = tid&63, li = L&15, lq = L>>4;
  int wr = w>>1, wc = w&1;
  int srow = tid>>2;
  int g8   = ((tid&3) ^ ((tid>>3)&3))*8;
  u16* AldsW = &Al[((tid&192))*8];
  u16* BldsW = &Bl[((tid&192))*8];
  int sw = (li>>1)&3;

  f4v acc[4][4];
  #pragma unroll
  for (int a=0;a<4;a++)
    #pragma unroll
    for (int c2=0;c2<4;c2++) acc[a][c2] = (f4v){0.f,0.f,0.f,0.f};

  for (int kk=0; kk<16; kk++){
    int k0 = kk*32;
    __syncthreads();
    #pragma unroll
    for (int c=0;c<2;c++){
      gl2lds16(&Abase[(size_t)(srow + c*64)*DM + k0 + g8], AldsW + c*2048);
      gl2lds16(&Bbase[(size_t)(srow + c*64)*DM + k0 + g8], BldsW + c*2048);
    }
    __syncthreads();
    s8v af[4], bfr[4];
    #pragma unroll
    for (int a=0;a<4;a++){
      int r = wr*64 + a*16 + li;
      af[a] = *(s8v*)&Al[r*32 + ((lq ^ sw))*8];
    }
    #pragma unroll
    for (int c2=0;c2<4;c2++){
      int r = wc*64 + c2*16 + li;
      bfr[c2] = *(s8v*)&Bl[r*32 + ((lq ^ sw))*8];
    }
    #pragma unroll
    for (int a=0;a<4;a++)
      #pragma unroll
      for (int c2=0;c2<4;c2++)
        acc[a][c2] = __builtin_amdgcn_mfma_f32_16x16x32_bf16(af[a], bfr[c2], acc[a][c2], 0, 0, 0);
  }

  if (t < 2){
    float scale = (t==0) ? 0.125f : 1.0f;
    // 2 passes of 64 cols (one head each): LDS-stage, then coalesced b128 stores
    #pragma unroll
    for (int p=0;p<2;p++){
      if (wc == p){
        #pragma unroll
        for (int c2=0;c2<4;c2++){
          int cl = c2*16 + li;
          float bias = bp[t*512 + o0 + p*64 + cl];
          #pragma unroll
          for (int a=0;a<4;a++)
            #pragma unroll
            for (int ri=0;ri<4;ri++)
              S[(wr*64 + a*16 + lq*4 + ri)*72 + cl] = f2bf((acc[a][c2][ri] + bias)*scale);
        }
      }
      __syncthreads();
      int row = tid>>1, cb = (tid&1)*32;
      int hh = (o0>>6) + p;
      u16* Pb = P + (((size_t)tb*NH + hh)*NN + r0 + row)*HD + cb;
      #pragma unroll
      for (int c=0;c<4;c++){
        s8v vv = *(s8v*)&S[row*72 + cb + c*8];
        *(s8v*)&Pb[c*8] = vv;
      }
      __syncthreads();
    }
  } else {
    // V: f16, tiled layout VT2[bh][m/16][d][m%16] (flash fragment-native)
    #pragma unroll
    for (int p=0;p<2;p++){
      if (wc == p){
        #pragma unroll
        for (int c2=0;c2<4;c2++){
          int cl = c2*16 + li;
          float bias = bp[2*512 + o0 + p*64 + cl];
          #pragma unroll
          for (int a=0;a<4;a++)
            #pragma unroll
            for (int ri=0;ri<4;ri++){
              _Float16 hh = (_Float16)(acc[a][c2][ri] + bias);
              S[(wr*64 + a*16 + lq*4 + ri)*72 + cl] = *(const u16*)&hh;
            }
        }
      }
      __syncthreads();
      int hh = (o0>>6) + p;
      u16* Vb = VT + (((size_t)b*NH + hh)*NN + r0)*HD;   // r0*64 = (r0/16)*1024
      #pragma unroll
      for (int it2=0; it2<4; it2++){
        int c = tid + it2*256;            // chunk 0..1023 (8 u16 each)
        int mb = c >> 7;                  // local m-block (16 m) 0..7
        int co = c & 127;
        int d  = co >> 1;
        int m8 = (co & 1)*8;
        u16 tmp[8];
        #pragma unroll
        for (int j=0;j<8;j++) tmp[j] = S[(mb*16 + m8 + j)*72 + d];
        *(s8v*)&Vb[(size_t)mb*1024 + d*16 + m8] = *(s8v*)&tmp[0];
      }
      __syncthreads();
    }
  }
}

// ---------------------------------------------------------------------------
// Kernel 4: bit-pack mask. allowed iff M==1.
// ---------------------------------------------------------------------------
__global__ void k_maskpack(const int* M, u64* bits){
  int tid = threadIdx.x;
  size_t word = (size_t)blockIdx.x*4 + (tid>>6);
  int lane = tid & 63;
  int v = M[word*64 + lane];
  u64 bal = __ballot(v == 1);
  if (lane == 0) bits[word] = bal;
}

// ---------------------------------------------------------------------------
// Kernel 4b: per-(b,ntile,mtile) AND of mask words -> fast-path flags.
// ---------------------------------------------------------------------------
__global__ __launch_bounds__(256) void k_maskand(const u64* bits, u64* allw){
  __shared__ u64 red[256];
  int bnt = blockIdx.x, tid = threadIdx.x;
  int mt = tid & 31, rg = tid >> 5;
  const u64* base = bits + (size_t)bnt*64*32;
  u64 v = ~0ull;
  #pragma unroll
  for (int j=0;j<8;j++) v &= base[(size_t)(rg*8+j)*32 + mt];
  red[tid] = v;
  __syncthreads();
  if (tid < 32){
    u64 a = red[tid];
    #pragma unroll
    for (int g2=1; g2<8; g2++) a &= red[g2*32 + tid];
    allw[(size_t)bnt*32 + tid] = a;
  }
}

// ---------------------------------------------------------------------------
// Kernel 5: transposed-S flash, barrier-free, EXPLICIT register pipeline.
// Wave w owns m-slice [w*16,w*16+16); K/V fragments loaded direct from
// global into double-buffered registers: iteration mt issues mt+1's loads
// before computing on mt -> one full iteration of compute hides L2 latency.
// V comes from the fragment-native tiled layout (512B contiguous per load).
// ---------------------------------------------------------------------------
__global__ __launch_bounds__(256) void k_flash(const u16* Pq, const u16* VT, const u64* bits,
                                               const u64* allw, u16* Xout){
  __shared__ __align__(16) char smem[18432 + 1024];
  float* Red = (float*)smem;               // [64][68] f32
  float* lsb = (float*)(smem + 18432);     // [4][64]

  int blk = blockIdx.x, tid = threadIdx.x;
  int nt = blk & 31; int bh = blk >> 5;
  int b = bh >> 3;
  int n0 = nt*64;
  const size_t TSZ = (size_t)BB*NH*NN*HD;
  const u16* Qb = Pq + ((size_t)bh*NN + n0)*HD;
  const u16* Kb = Pq + TSZ + (size_t)bh*NN*HD;
  const u16* Vb = VT + (size_t)bh*NN*HD;          // tiled [m/16][d][m%16] f16
  const u64* awp = allw + ((size_t)b*32 + nt)*32;

  int w = tid>>6, L = tid&63, li = L&15, lq = L>>4;

  // Q fragments in registers (loop-invariant)
  s8v Qf[4][2];
  #pragma unroll
  for (int j=0;j<4;j++)
    #pragma unroll
    for (int h2=0;h2<2;h2++)
      Qf[j][h2] = *(const s8v*)&Qb[(size_t)(j*16+li)*HD + h2*32 + lq*8];

  f4v O[4][4];     // O^T partial: [d-block j2][n-block j]
  #pragma unroll
  for (int j2=0;j2<4;j2++)
    #pragma unroll
    for (int j=0;j<4;j++) O[j2][j] = (f4v){0.f,0.f,0.f,0.f};
  float ls[4] = {0.f,0.f,0.f,0.f};

  const u16* Krow = Kb + (size_t)(w*16 + li)*HD + lq*8;   // + mt*4096
  const u16* Vrow = Vb + (size_t)w*1024 + li*16 + lq*4;   // + mt*4096 + j2*256

  // prefetch mt=0
  s8v cK0 = *(const s8v*)&Krow[0];
  s8v cK1 = *(const s8v*)&Krow[32];
  h4 cV[4];
  #pragma unroll
  for (int j2=0;j2<4;j2++) cV[j2] = *(const h4*)&Vrow[j2*256];

  for (int mt=0; mt<32; mt++){
    // issue next iteration's loads first (wrap avoids branch; redundant last iter)
    size_t noff = (size_t)((mt+1)&31)*4096;
    s8v nK0 = *(const s8v*)&Krow[noff];
    s8v nK1 = *(const s8v*)&Krow[noff + 32];
    h4 nV[4];
    #pragma unroll
    for (int j2=0;j2<4;j2++) nV[j2] = *(const h4*)&Vrow[noff + j2*256];

    u64 aw = awp[mt];
    bool fast = (aw == ~0ull);

    // S^T[m=w-slice][n] = K Q^T : lane holds P[n=j*16+li][m=lq*4+r]
    f4v S[4];
    #pragma unroll
    for (int j=0;j<4;j++){
      f4v c = (f4v){0.f,0.f,0.f,0.f};
      c = __builtin_amdgcn_mfma_f32_16x16x32_bf16(cK0, Qf[j][0], c, 0, 0, 0);
      c = __builtin_amdgcn_mfma_f32_16x16x32_bf16(cK1, Qf[j][1], c, 0, 0, 0);
      S[j] = c;
    }

    // exp (+mask), accumulate partials, pack to f16 B-fragments
    h4 Pf[4];
    if (fast){
      #pragma unroll
      for (int j=0;j<4;j++){
        float e0 = __expf(S[j][0]), e1 = __expf(S[j][1]);
        float e2 = __expf(S[j][2]), e3 = __expf(S[j][3]);
        ls[j] += (e0+e1)+(e2+e3);
        Pf[j][0] = (_Float16)e0; Pf[j][1] = (_Float16)e1;
        Pf[j][2] = (_Float16)e2; Pf[j][3] = (_Float16)e3;
      }
    } else {
      int mbit = w*16 + lq*4;
      #pragma unroll
      for (int j=0;j<4;j++){
        u64 mw = bits[((size_t)b*NN + n0 + j*16 + li)*32 + mt];
        float e[4];
        #pragma unroll
        for (int r=0;r<4;r++){
          float ev = __expf(S[j][r]);
          e[r] = ((mw>>(mbit+r)) & 1ull) ? ev : 0.f;
          Pf[j][r] = (_Float16)e[r];
        }
        ls[j] += (e[0]+e[1])+(e[2]+e[3]);
      }
    }

    // O^T += V^T P (all operands in registers)
    #pragma unroll
    for (int j2=0;j2<4;j2++)
      #pragma unroll
      for (int j=0;j<4;j++)
        O[j2][j] = __builtin_amdgcn_mfma_f32_16x16x16f16(cV[j2], Pf[j], O[j2][j], 0, 0, 0);

    cK0 = nK0; cK1 = nK1;
    #pragma unroll
    for (int j2=0;j2<4;j2++) cV[j2] = nV[j2];
  }

  // reduce ls over lq (lanes li, li+16, li+32, li+48)
  #pragma unroll
  for (int j=0;j<4;j++){
    float r = ls[j];
    r += __shfl_xor(r, 16); r += __shfl_xor(r, 32);
    ls[j] = r;
  }
  if (lq == 0){
    #pragma unroll
    for (int j=0;j<4;j++) lsb[w*64 + j*16 + li] = ls[j];
  }
  __syncthreads();

  // cross-wave O^T reduction into Red[n][d] (4 phases)
  #pragma unroll
  for (int ph=0; ph<4; ph++){
    if (w == ph){
      #pragma unroll
      for (int j=0;j<4;j++)
        #pragma unroll
        for (int j2=0;j2<4;j2++){
          f4v* p = (f4v*)&Red[(j*16+li)*68 + j2*16 + lq*4];
          if (ph == 0) *p = O[j2][j];
          else { f4v t = *p; t += O[j2][j]; *p = t; }
        }
    }
    __syncthreads();
  }

  // normalize + write Xout[b][n][h*64+d]
  int n = tid>>2, d0 = (tid&3)*16;
  float s = lsb[n] + lsb[64+n] + lsb[128+n] + lsb[192+n];
  float inv = (s > 0.f) ? 1.0f/s : 0.f;
  int h = bh & 7;
  u16* Xo = Xout + ((size_t)b*NN + n0 + n)*DM + h*HD + d0;
  u16 tmp[16];
  #pragma unroll
  for (int e2=0;e2<4;e2++){
    f4v vv = *(f4v*)&Red[n*68 + d0 + e2*4];
    #pragma unroll
    for (int q2=0;q2<4;q2++) tmp[e2*4+q2] = f2bf(vv[q2]*inv);
  }
  *(s8v*)&Xo[0] = *(s8v*)&tmp[0];
  *(s8v*)&Xo[8] = *(s8v*)&tmp[8];
}

// ---------------------------------------------------------------------------
// Kernel 6: output GEMM, 64(o) x 128(n) tiles -> 512 blocks (2/CU).
// A=Wmp (o rows), B=Xout (n rows). out[b][o][n] = acc + bm[o] (f32)
// ---------------------------------------------------------------------------
__global__ __launch_bounds__(256) void k_out(const u16* Wmp, const u16* Xout, const float* bm, float* out){
  __shared__ u16 Al[64*32];
  __shared__ u16 Bl[128*32];
  int blk = blockIdx.x, tid = threadIdx.x;
  int nt = blk & 15; blk >>= 4;
  int ot = blk & 7;  int b = blk >> 3;
  int o0 = ot*64, n0 = nt*128;
  const u16* Abase = Wmp + (size_t)o0*DM;
  const u16* Bbase = Xout + ((size_t)b*NN + n0)*DM;

  int w = tid>>6, L = tid&63, li = L&15, lq = L>>4;
  int wo = w&1, wn = w>>1;
  int srow = tid>>2;
  int g8   = ((tid&3) ^ ((tid>>3)&3))*8;
  u16* AldsW = &Al[((tid&192))*8];
  u16* BldsW = &Bl[((tid&192))*8];
  int sw = (li>>1)&3;

  f4v acc[2][4];
  #pragma unroll
  for (int a=0;a<2;a++)
    #pragma unroll
    for (int c2=0;c2<4;c2++) acc[a][c2] = (f4v){0.f,0.f,0.f,0.f};

  for (int kk=0; kk<16; kk++){
    int k0 = kk*32;
    __syncthreads();
    gl2lds16(&Abase[(size_t)srow*DM + k0 + g8], AldsW);
    #pragma unroll
    for (int c=0;c<2;c++)
      gl2lds16(&Bbase[(size_t)(srow + c*64)*DM + k0 + g8], BldsW + c*2048);
    __syncthreads();
    s8v af[2], bfr[4];
    #pragma unroll
    for (int a=0;a<2;a++){
      int r = wo*32 + a*16 + li;
      af[a] = *(s8v*)&Al[r*32 + ((lq ^ sw))*8];
    }
    #pragma unroll
    for (int c2=0;c2<4;c2++){
      int r = wn*64 + c2*16 + li;
      bfr[c2] = *(s8v*)&Bl[r*32 + ((lq ^ sw))*8];
    }
    #pragma unroll
    for (int a=0;a<2;a++)
      #pragma unroll
      for (int c2=0;c2<4;c2++)
        acc[a][c2] = __builtin_amdgcn_mfma_f32_16x16x32_bf16(af[a], bfr[c2], acc[a][c2], 0, 0, 0);
  }

  #pragma unroll
  for (int a=0;a<2;a++){
    #pragma unroll
    for (int ri=0;ri<4;ri++){
      int o = o0 + wo*32 + a*16 + lq*4 + ri;
      float bias = bm[o];
      float* ob = out + ((size_t)b*DM + o)*NN + n0 + wn*64;
      #pragma unroll
      for (int c2=0;c2<4;c2++)
        ob[c2*16 + li] = acc[a][c2][ri] + bias;
    }
  }
}

// ---------------------------------------------------------------------------
extern "C" void kernel_launch(void* const* d_in, const int* in_sizes, int n_in,
                              void* d_out, int out_size, void* d_ws, size_t ws_size,
                              hipStream_t stream){
  const float* q  = (const float*)d_in[0];
  const float* k  = (const float*)d_in[1];
  const float* v  = (const float*)d_in[2];
  const int*   M  = (const int*)d_in[3];
  const float* Wq = (const float*)d_in[4];
  const float* bq = (const float*)d_in[5];
  const float* Wk = (const float*)d_in[6];
  const float* bk = (const float*)d_in[7];
  const float* Wv = (const float*)d_in[8];
  const float* bv = (const float*)d_in[9];
  const float* Wm = (const float*)d_in[10];
  const float* bm = (const float*)d_in[11];

  char* ws = (char*)d_ws;
  u16*   XT   = (u16*)(ws + 0);            // 25,165,824
  u16*   P    = (u16*)(ws + 25165824);     // Q,K: 16,777,216
  u16*   VT   = (u16*)(ws + 41943040);     //  8,388,608 (f16, tiled)
  u16*   Wp   = (u16*)(ws + 50331648);     //  1,572,864
  u16*   Wmp  = (u16*)(ws + 51904512);     //    524,288
  float* bp   = (float*)(ws + 52428800);   //      6,144
  u64*   bits = (u64*)(ws + 52434944);     //  2,097,152
  u16*   Xout = (u16*)(ws + 54532096);     //  8,388,608
  u64*   allw = (u64*)(ws + 62920704);     //     32,768
  float* out  = (float*)d_out;

  k_permute<<<2049, 256, 0, stream>>>(Wq, bq, Wk, bk, Wv, bv, Wm, Wp, Wmp, bp);
  k_transpose<<<3072, 256, 0, stream>>>(q, k, v, XT);
  k_proj<<<768, 256, 0, stream>>>(XT, Wp, bp, P, VT);
  k_maskpack<<<65536, 256, 0, stream>>>(M, bits);
  k_maskand<<<128, 256, 0, stream>>>(bits, allw);
  k_flash<<<1024, 256, 0, stream>>>(P, VT, bits, allw, Xout);
  k_out<<<512, 256, 0, stream>>>(Wmp, Xout, bm, out);
}

// Round 8
// 274.955 us; speedup vs baseline: 1.1849x; 1.0410x over previous
//
#include <hip/hip_runtime.h>

typedef __attribute__((ext_vector_type(8))) short s8v;   // 8 x bf16 (4 VGPRs)
typedef __attribute__((ext_vector_type(4))) float f4v;   // MFMA accumulator
typedef _Float16 h4 __attribute__((ext_vector_type(4))); // 4 x f16 (2 VGPRs)
typedef unsigned short u16;
typedef unsigned long long u64;

#define DM 512
#define NH 8
#define HD 64
#define BB 4
#define NN 2048

__device__ __forceinline__ float bf2f(u16 x){ return __uint_as_float(((unsigned)x)<<16); }
__device__ __forceinline__ u16 f2bf(float f){
  unsigned u = __float_as_uint(f);
  u += 0x7FFFu + ((u>>16)&1u);            // round-to-nearest-even
  return (u16)(u>>16);
}
// async global->LDS, 16B per lane; LDS dest = wave-uniform base + lane*16
__device__ __forceinline__ void gl2lds16(const u16* g, u16* l){
  __builtin_amdgcn_global_load_lds((__attribute__((address_space(1))) void*)(g),
                                   (__attribute__((address_space(3))) void*)(l), 16, 0, 0);
}

// ---------------------------------------------------------------------------
// Kernel 1: maskpack, fat blocks. allowed iff M==1. 4096 blocks x 64 words.
// ---------------------------------------------------------------------------
__global__ __launch_bounds__(256) void k_maskpack(const int* M, u64* bits){
  int tid = threadIdx.x;
  int wv = tid>>6, lane = tid&63;
  size_t w0 = (size_t)blockIdx.x*64 + wv*16;
  #pragma unroll
  for (int it=0; it<16; it++){
    int v = M[(w0+it)*64 + lane];
    u64 bal = __ballot(v == 1);
    if (lane == 0) bits[w0+it] = bal;
  }
}

// ---------------------------------------------------------------------------
// Kernel 2: prep = weight permute/convert (blk<2049) + mask tile-AND (rest).
// Runs after k_maskpack (needs bits).
// ---------------------------------------------------------------------------
__global__ void k_prep(const float* Wq, const float* bq, const float* Wk, const float* bk,
                       const float* Wv, const float* bv, const float* Wm,
                       u16* Wp, u16* Wmp, float* bp,
                       const u64* bits, u64* allw){
  int blk = blockIdx.x, tid = threadIdx.x;
  if (blk < 1536){
    int t = blk >> 9, op = blk & 511;
    int srow = ((op & 63) << 3) | (op >> 6);
    const float* W = (t==0) ? Wq : ((t==1) ? Wk : Wv);
    for (int j = tid; j < 512; j += 256)
      Wp[((size_t)t*512 + op)*512 + j] = f2bf(W[(size_t)srow*512 + j]);
  } else if (blk < 2048){
    int o = blk - 1536;
    for (int c = tid; c < 512; c += 256){
      int scol = ((c & 63) << 3) | (c >> 6);
      Wmp[(size_t)o*512 + c] = f2bf(Wm[(size_t)o*512 + scol]);
    }
  } else if (blk == 2048){
    for (int idx = tid; idx < 1536; idx += 256){
      int t = idx >> 9, op = idx & 511;
      const float* bs = (t==0) ? bq : ((t==1) ? bk : bv);
      int srow = ((op & 63) << 3) | (op >> 6);
      bp[idx] = bs[srow];
    }
  } else {
    __shared__ u64 red[256];
    int bnt = blk - 2049;
    int mt = tid & 31, rg = tid >> 5;
    const u64* base = bits + (size_t)bnt*64*32;
    u64 v = ~0ull;
    #pragma unroll
    for (int j=0;j<8;j++) v &= base[(size_t)(rg*8+j)*32 + mt];
    red[tid] = v;
    __syncthreads();
    if (tid < 32){
      u64 a = red[tid];
      #pragma unroll
      for (int g2=1; g2<8; g2++) a &= red[g2*32 + tid];
      allw[(size_t)bnt*32 + tid] = a;
    }
  }
}

// ---------------------------------------------------------------------------
// Kernel 3: transpose + convert inputs  f32 [b][i][r] -> bf16 XT[t][b][r][i]
// ---------------------------------------------------------------------------
__global__ __launch_bounds__(256) void k_transpose(const float* q, const float* k, const float* v, u16* XT){
  __shared__ u16 T[64*72];
  int blk = blockIdx.x, tid = threadIdx.x;
  int rt = blk & 31; blk >>= 5;
  int it = blk & 7;  blk >>= 3;
  int b  = blk & 3;  int t = blk >> 2;
  const float* src = (t==0) ? q : ((t==1) ? k : v);
  src += (size_t)b*DM*NN;
  int i0 = it*64, r0 = rt*64;
  int il = tid>>4, rj = (tid&15)*4;
  #pragma unroll
  for (int p=0;p<4;p++){
    int i = il + p*16;
    float4 vv = *(const float4*)&src[(size_t)(i0+i)*NN + r0 + rj];
    float fv[4] = {vv.x, vv.y, vv.z, vv.w};
    #pragma unroll
    for (int qq=0;qq<4;qq++){
      int r = rj + qq;
      int sr = ((r&3)<<4) | (r>>2);
      T[sr*72 + i] = f2bf(fv[qq]);
    }
  }
  __syncthreads();
  u16* dst = XT + ((size_t)(t*4+b)*NN)*DM;
  int rl = tid>>3, ib = (tid&7)*8;
  #pragma unroll
  for (int p=0;p<2;p++){
    int r = rl + p*32;
    int sr = ((r&3)<<4) | (r>>2);
    s8v vv = *(s8v*)&T[sr*72 + ib];
    *(s8v*)&dst[(size_t)(r0+r)*DM + i0 + ib] = vv;
  }
}

// ---------------------------------------------------------------------------
// Kernel 4: projection GEMM, m97-style 128x128 tile, BK=32, global_load_lds.
// t=0 (Q, scaled 1/8) / t=1 (K) -> P[t*4+b][h][r][d] bf16 (LDS-staged, coalesced)
// t=2 (V) -> VT2[b][h][m/16][d][m%16]  f16, fragment-native tiled layout
// ---------------------------------------------------------------------------
__global__ __launch_bounds__(256) void k_proj(const u16* XT, const u16* Wp, const float* bp,
                                              u16* P, u16* VT){
  __shared__ u16 Al[128*32];
  __shared__ u16 Bl[128*32];
  __shared__ u16 S[128*72];
  int blk = blockIdx.x, tid = threadIdx.x;
  int nt = blk & 3; int mt = blk >> 2;      // 192 M-tiles
  int tb = mt >> 4;                         // t*4+b
  int t  = tb >> 2, b = tb & 3;
  int r0 = (mt & 15)*128, o0 = nt*128;
  const u16* Abase = XT + ((size_t)tb*NN + r0)*DM;
  const u16* Bbase = Wp + ((size_t)t*512 + o0)*DM;

  int w = tid>>6, L = tid&63, li = L&15, lq = L>>4;
  int wr = w>>1, wc = w&1;
  int srow = tid>>2;
  int g8   = ((tid&3) ^ ((tid>>3)&3))*8;
  u16* AldsW = &Al[((tid&192))*8];
  u16* BldsW = &Bl[((tid&192))*8];
  int sw = (li>>1)&3;

  f4v acc[4][4];
  #pragma unroll
  for (int a=0;a<4;a++)
    #pragma unroll
    for (int c2=0;c2<4;c2++) acc[a][c2] = (f4v){0.f,0.f,0.f,0.f};

  for (int kk=0; kk<16; kk++){
    int k0 = kk*32;
    __syncthreads();
    #pragma unroll
    for (int c=0;c<2;c++){
      gl2lds16(&Abase[(size_t)(srow + c*64)*DM + k0 + g8], AldsW + c*2048);
      gl2lds16(&Bbase[(size_t)(srow + c*64)*DM + k0 + g8], BldsW + c*2048);
    }
    __syncthreads();
    s8v af[4], bfr[4];
    #pragma unroll
    for (int a=0;a<4;a++){
      int r = wr*64 + a*16 + li;
      af[a] = *(s8v*)&Al[r*32 + ((lq ^ sw))*8];
    }
    #pragma unroll
    for (int c2=0;c2<4;c2++){
      int r = wc*64 + c2*16 + li;
      bfr[c2] = *(s8v*)&Bl[r*32 + ((lq ^ sw))*8];
    }
    #pragma unroll
    for (int a=0;a<4;a++)
      #pragma unroll
      for (int c2=0;c2<4;c2++)
        acc[a][c2] = __builtin_amdgcn_mfma_f32_16x16x32_bf16(af[a], bfr[c2], acc[a][c2], 0, 0, 0);
  }

  if (t < 2){
    float scale = (t==0) ? 0.125f : 1.0f;
    // 2 passes of 64 cols (one head each): LDS-stage, then coalesced b128 stores
    #pragma unroll
    for (int p=0;p<2;p++){
      if (wc == p){
        #pragma unroll
        for (int c2=0;c2<4;c2++){
          int cl = c2*16 + li;
          float bias = bp[t*512 + o0 + p*64 + cl];
          #pragma unroll
          for (int a=0;a<4;a++)
            #pragma unroll
            for (int ri=0;ri<4;ri++)
              S[(wr*64 + a*16 + lq*4 + ri)*72 + cl] = f2bf((acc[a][c2][ri] + bias)*scale);
        }
      }
      __syncthreads();
      int row = tid>>1, cb = (tid&1)*32;
      int hh = (o0>>6) + p;
      u16* Pb = P + (((size_t)tb*NH + hh)*NN + r0 + row)*HD + cb;
      #pragma unroll
      for (int c=0;c<4;c++){
        s8v vv = *(s8v*)&S[row*72 + cb + c*8];
        *(s8v*)&Pb[c*8] = vv;
      }
      __syncthreads();
    }
  } else {
    // V: f16, tiled layout VT2[bh][m/16][d][m%16] (flash fragment-native)
    #pragma unroll
    for (int p=0;p<2;p++){
      if (wc == p){
        #pragma unroll
        for (int c2=0;c2<4;c2++){
          int cl = c2*16 + li;
          float bias = bp[2*512 + o0 + p*64 + cl];
          #pragma unroll
          for (int a=0;a<4;a++)
            #pragma unroll
            for (int ri=0;ri<4;ri++){
              _Float16 hh = (_Float16)(acc[a][c2][ri] + bias);
              S[(wr*64 + a*16 + lq*4 + ri)*72 + cl] = *(const u16*)&hh;
            }
        }
      }
      __syncthreads();
      int hh = (o0>>6) + p;
      u16* Vb = VT + (((size_t)b*NH + hh)*NN + r0)*HD;   // r0*64 = (r0/16)*1024
      #pragma unroll
      for (int it2=0; it2<4; it2++){
        int c = tid + it2*256;            // chunk 0..1023 (8 u16 each)
        int mb = c >> 7;                  // local m-block (16 m) 0..7
        int co = c & 127;
        int d  = co >> 1;
        int m8 = (co & 1)*8;
        u16 tmp[8];
        #pragma unroll
        for (int j=0;j<8;j++) tmp[j] = S[(mb*16 + m8 + j)*72 + d];
        *(s8v*)&Vb[(size_t)mb*1024 + d*16 + m8] = *(s8v*)&tmp[0];
      }
      __syncthreads();
    }
  }
}

// ---------------------------------------------------------------------------
// Kernel 5: transposed-S flash, barrier-free, register pipeline, XCD-local.
// Block decode: bh = blk&31, nt = blk>>5 -> same-bh blocks have IDs stride 32
// -> land on the SAME XCD under %8 round-robin -> K/V (2 MB per 4 bh) stay
// resident in that XCD's 4 MB L2; all re-reads are L2 hits.
// ---------------------------------------------------------------------------
__global__ __launch_bounds__(256) void k_flash(const u16* Pq, const u16* VT, const u64* bits,
                                               const u64* allw, u16* Xout){
  __shared__ __align__(16) char smem[18432 + 1024];
  float* Red = (float*)smem;               // [64][68] f32
  float* lsb = (float*)(smem + 18432);     // [4][64]

  int blk = blockIdx.x, tid = threadIdx.x;
  int bh = blk & 31; int nt = blk >> 5;
  int b = bh >> 3;
  int n0 = nt*64;
  const size_t TSZ = (size_t)BB*NH*NN*HD;
  const u16* Qb = Pq + ((size_t)bh*NN + n0)*HD;
  const u16* Kb = Pq + TSZ + (size_t)bh*NN*HD;
  const u16* Vb = VT + (size_t)bh*NN*HD;          // tiled [m/16][d][m%16] f16
  const u64* awp = allw + ((size_t)b*32 + nt)*32;

  int w = tid>>6, L = tid&63, li = L&15, lq = L>>4;

  // Q fragments in registers (loop-invariant)
  s8v Qf[4][2];
  #pragma unroll
  for (int j=0;j<4;j++)
    #pragma unroll
    for (int h2=0;h2<2;h2++)
      Qf[j][h2] = *(const s8v*)&Qb[(size_t)(j*16+li)*HD + h2*32 + lq*8];

  f4v O[4][4];     // O^T partial: [d-block j2][n-block j]
  #pragma unroll
  for (int j2=0;j2<4;j2++)
    #pragma unroll
    for (int j=0;j<4;j++) O[j2][j] = (f4v){0.f,0.f,0.f,0.f};
  float ls[4] = {0.f,0.f,0.f,0.f};

  const u16* Krow = Kb + (size_t)(w*16 + li)*HD + lq*8;   // + mt*4096
  const u16* Vrow = Vb + (size_t)w*1024 + li*16 + lq*4;   // + mt*4096 + j2*256

  // prefetch mt=0
  s8v cK0 = *(const s8v*)&Krow[0];
  s8v cK1 = *(const s8v*)&Krow[32];
  h4 cV[4];
  #pragma unroll
  for (int j2=0;j2<4;j2++) cV[j2] = *(const h4*)&Vrow[j2*256];

  for (int mt=0; mt<32; mt++){
    // issue next iteration's loads first (wrap avoids branch; redundant last iter)
    size_t noff = (size_t)((mt+1)&31)*4096;
    s8v nK0 = *(const s8v*)&Krow[noff];
    s8v nK1 = *(const s8v*)&Krow[noff + 32];
    h4 nV[4];
    #pragma unroll
    for (int j2=0;j2<4;j2++) nV[j2] = *(const h4*)&Vrow[noff + j2*256];

    u64 aw = awp[mt];
    bool fast = (aw == ~0ull);

    // S^T[m=w-slice][n] = K Q^T : lane holds P[n=j*16+li][m=lq*4+r]
    f4v S[4];
    #pragma unroll
    for (int j=0;j<4;j++){
      f4v c = (f4v){0.f,0.f,0.f,0.f};
      c = __builtin_amdgcn_mfma_f32_16x16x32_bf16(cK0, Qf[j][0], c, 0, 0, 0);
      c = __builtin_amdgcn_mfma_f32_16x16x32_bf16(cK1, Qf[j][1], c, 0, 0, 0);
      S[j] = c;
    }

    // exp (+mask), accumulate partials, pack to f16 B-fragments
    h4 Pf[4];
    if (fast){
      #pragma unroll
      for (int j=0;j<4;j++){
        float e0 = __expf(S[j][0]), e1 = __expf(S[j][1]);
        float e2 = __expf(S[j][2]), e3 = __expf(S[j][3]);
        ls[j] += (e0+e1)+(e2+e3);
        Pf[j][0] = (_Float16)e0; Pf[j][1] = (_Float16)e1;
        Pf[j][2] = (_Float16)e2; Pf[j][3] = (_Float16)e3;
      }
    } else {
      int mbit = w*16 + lq*4;
      #pragma unroll
      for (int j=0;j<4;j++){
        u64 mw = bits[((size_t)b*NN + n0 + j*16 + li)*32 + mt];
        float e[4];
        #pragma unroll
        for (int r=0;r<4;r++){
          float ev = __expf(S[j][r]);
          e[r] = ((mw>>(mbit+r)) & 1ull) ? ev : 0.f;
          Pf[j][r] = (_Float16)e[r];
        }
        ls[j] += (e[0]+e[1])+(e[2]+e[3]);
      }
    }

    // O^T += V^T P (all operands in registers)
    #pragma unroll
    for (int j2=0;j2<4;j2++)
      #pragma unroll
      for (int j=0;j<4;j++)
        O[j2][j] = __builtin_amdgcn_mfma_f32_16x16x16f16(cV[j2], Pf[j], O[j2][j], 0, 0, 0);

    cK0 = nK0; cK1 = nK1;
    #pragma unroll
    for (int j2=0;j2<4;j2++) cV[j2] = nV[j2];
  }

  // reduce ls over lq (lanes li, li+16, li+32, li+48)
  #pragma unroll
  for (int j=0;j<4;j++){
    float r = ls[j];
    r += __shfl_xor(r, 16); r += __shfl_xor(r, 32);
    ls[j] = r;
  }
  if (lq == 0){
    #pragma unroll
    for (int j=0;j<4;j++) lsb[w*64 + j*16 + li] = ls[j];
  }
  __syncthreads();

  // cross-wave O^T reduction into Red[n][d] (4 phases)
  #pragma unroll
  for (int ph=0; ph<4; ph++){
    if (w == ph){
      #pragma unroll
      for (int j=0;j<4;j++)
        #pragma unroll
        for (int j2=0;j2<4;j2++){
          f4v* p = (f4v*)&Red[(j*16+li)*68 + j2*16 + lq*4];
          if (ph == 0) *p = O[j2][j];
          else { f4v t = *p; t += O[j2][j]; *p = t; }
        }
    }
    __syncthreads();
  }

  // normalize + write Xout[b][n][h*64+d]
  int n = tid>>2, d0 = (tid&3)*16;
  float s = lsb[n] + lsb[64+n] + lsb[128+n] + lsb[192+n];
  float inv = (s > 0.f) ? 1.0f/s : 0.f;
  int h = bh & 7;
  u16* Xo = Xout + ((size_t)b*NN + n0 + n)*DM + h*HD + d0;
  u16 tmp[16];
  #pragma unroll
  for (int e2=0;e2<4;e2++){
    f4v vv = *(f4v*)&Red[n*68 + d0 + e2*4];
    #pragma unroll
    for (int q2=0;q2<4;q2++) tmp[e2*4+q2] = f2bf(vv[q2]*inv);
  }
  *(s8v*)&Xo[0] = *(s8v*)&tmp[0];
  *(s8v*)&Xo[8] = *(s8v*)&tmp[8];
}

// ---------------------------------------------------------------------------
// Kernel 6: output GEMM, 64(o) x 128(n) tiles -> 512 blocks (2/CU).
// A=Wmp (o rows), B=Xout (n rows). out[b][o][n] = acc + bm[o] (f32)
// ---------------------------------------------------------------------------
__global__ __launch_bounds__(256) void k_out(const u16* Wmp, const u16* Xout, const float* bm, float* out){
  __shared__ u16 Al[64*32];
  __shared__ u16 Bl[128*32];
  int blk = blockIdx.x, tid = threadIdx.x;
  int nt = blk & 15; blk >>= 4;
  int ot = blk & 7;  int b = blk >> 3;
  int o0 = ot*64, n0 = nt*128;
  const u16* Abase = Wmp + (size_t)o0*DM;
  const u16* Bbase = Xout + ((size_t)b*NN + n0)*DM;

  int w = tid>>6, L = tid&63, li = L&15, lq = L>>4;
  int wo = w&1, wn = w>>1;
  int srow = tid>>2;
  int g8   = ((tid&3) ^ ((tid>>3)&3))*8;
  u16* AldsW = &Al[((tid&192))*8];
  u16* BldsW = &Bl[((tid&192))*8];
  int sw = (li>>1)&3;

  f4v acc[2][4];
  #pragma unroll
  for (int a=0;a<2;a++)
    #pragma unroll
    for (int c2=0;c2<4;c2++) acc[a][c2] = (f4v){0.f,0.f,0.f,0.f};

  for (int kk=0; kk<16; kk++){
    int k0 = kk*32;
    __syncthreads();
    gl2lds16(&Abase[(size_t)srow*DM + k0 + g8], AldsW);
    #pragma unroll
    for (int c=0;c<2;c++)
      gl2lds16(&Bbase[(size_t)(srow + c*64)*DM + k0 + g8], BldsW + c*2048);
    __syncthreads();
    s8v af[2], bfr[4];
    #pragma unroll
    for (int a=0;a<2;a++){
      int r = wo*32 + a*16 + li;
      af[a] = *(s8v*)&Al[r*32 + ((lq ^ sw))*8];
    }
    #pragma unroll
    for (int c2=0;c2<4;c2++){
      int r = wn*64 + c2*16 + li;
      bfr[c2] = *(s8v*)&Bl[r*32 + ((lq ^ sw))*8];
    }
    #pragma unroll
    for (int a=0;a<2;a++)
      #pragma unroll
      for (int c2=0;c2<4;c2++)
        acc[a][c2] = __builtin_amdgcn_mfma_f32_16x16x32_bf16(af[a], bfr[c2], acc[a][c2], 0, 0, 0);
  }

  #pragma unroll
  for (int a=0;a<2;a++){
    #pragma unroll
    for (int ri=0;ri<4;ri++){
      int o = o0 + wo*32 + a*16 + lq*4 + ri;
      float bias = bm[o];
      float* ob = out + ((size_t)b*DM + o)*NN + n0 + wn*64;
      #pragma unroll
      for (int c2=0;c2<4;c2++)
        ob[c2*16 + li] = acc[a][c2][ri] + bias;
    }
  }
}

// ---------------------------------------------------------------------------
extern "C" void kernel_launch(void* const* d_in, const int* in_sizes, int n_in,
                              void* d_out, int out_size, void* d_ws, size_t ws_size,
                              hipStream_t stream){
  const float* q  = (const float*)d_in[0];
  const float* k  = (const float*)d_in[1];
  const float* v  = (const float*)d_in[2];
  const int*   M  = (const int*)d_in[3];
  const float* Wq = (const float*)d_in[4];
  const float* bq = (const float*)d_in[5];
  const float* Wk = (const float*)d_in[6];
  const float* bk = (const float*)d_in[7];
  const float* Wv = (const float*)d_in[8];
  const float* bv = (const float*)d_in[9];
  const float* Wm = (const float*)d_in[10];
  const float* bm = (const float*)d_in[11];

  char* ws = (char*)d_ws;
  u16*   XT   = (u16*)(ws + 0);            // 25,165,824
  u16*   P    = (u16*)(ws + 25165824);     // Q,K: 16,777,216
  u16*   VT   = (u16*)(ws + 41943040);     //  8,388,608 (f16, tiled)
  u16*   Wp   = (u16*)(ws + 50331648);     //  1,572,864
  u16*   Wmp  = (u16*)(ws + 51904512);     //    524,288
  float* bp   = (float*)(ws + 52428800);   //      6,144
  u64*   bits = (u64*)(ws + 52434944);     //  2,097,152
  u16*   Xout = (u16*)(ws + 54532096);     //  8,388,608
  u64*   allw = (u64*)(ws + 62920704);     //     32,768
  float* out  = (float*)d_out;

  k_maskpack<<<4096, 256, 0, stream>>>(M, bits);
  k_prep<<<2177, 256, 0, stream>>>(Wq, bq, Wk, bk, Wv, bv, Wm, Wp, Wmp, bp, bits, allw);
  k_transpose<<<3072, 256, 0, stream>>>(q, k, v, XT);
  k_proj<<<768, 256, 0, stream>>>(XT, Wp, bp, P, VT);
  k_flash<<<1024, 256, 0, stream>>>(P, VT, bits, allw, Xout);
  k_out<<<512, 256, 0, stream>>>(Wmp, Xout, bm, out);
}